// Round 10
// baseline (323.476 us; speedup 1.0000x reference)
//
#include <hip/hip_runtime.h>
#include <stdint.h>

#define S_LEN 4096
#define HDIM  2048
#define NHEAD 16
#define HD    128
#define WIN   1024

typedef float  f32x4  __attribute__((ext_vector_type(4)));
typedef float  f32x4v __attribute__((ext_vector_type(4)));
typedef __bf16 bf16x8 __attribute__((ext_vector_type(8)));
typedef short  short8 __attribute__((ext_vector_type(8)));
typedef short  short4v __attribute__((ext_vector_type(4)));

static __device__ __forceinline__ short f2bf(float f) {
  union { float f; uint32_t u; } v; v.f = f;
  uint32_t r = (v.u + 0x7FFFu + ((v.u >> 16) & 1u)) >> 16;
  return (short)(uint16_t)r;
}

static __device__ __forceinline__ void gload_lds16(const void* g, void* l) {
  __builtin_amdgcn_global_load_lds((__attribute__((address_space(1))) void*)g,
                                   (__attribute__((address_space(3))) void*)l,
                                   16, 0, 0);
}

// ---------------- RMSNorm: f32 x (4096x2048) -> bf16 xn ----------------
__global__ __launch_bounds__(256) void rmsnorm_k(const float* __restrict__ x,
                                                 const float* __restrict__ w,
                                                 short* __restrict__ xn) {
  const int row = blockIdx.x;
  const int t = threadIdx.x;
  const float* xr = x + (size_t)row * HDIM;
  f32x4v a = *(const f32x4v*)&xr[t * 8];
  f32x4v b = *(const f32x4v*)&xr[t * 8 + 4];
  float ss = a.x*a.x + a.y*a.y + a.z*a.z + a.w*a.w
           + b.x*b.x + b.y*b.y + b.z*b.z + b.w*b.w;
#pragma unroll
  for (int d = 1; d < 64; d <<= 1) ss += __shfl_xor(ss, d, 64);
  __shared__ float sred[4];
  if ((t & 63) == 0) sred[t >> 6] = ss;
  __syncthreads();
  float tot = sred[0] + sred[1] + sred[2] + sred[3];
  float rs = rsqrtf(tot * (1.0f / HDIM) + 1e-5f);
  float vv[8] = {a.x, a.y, a.z, a.w, b.x, b.y, b.z, b.w};
  const float* wp = w + t * 8;
  short8 o;
#pragma unroll
  for (int j = 0; j < 8; ++j) o[j] = f2bf(vv[j] * rs * wp[j]);
  *(short8*)&xn[(size_t)row * HDIM + t * 8] = o;
}

// ---------------- f32 -> bf16 weight convert ----------------
__global__ __launch_bounds__(256) void cvt_k(const float* __restrict__ in,
                                             short* __restrict__ out, int n4) {
  int i = blockIdx.x * 256 + threadIdx.x;
  if (i >= n4) return;
  f32x4v v = *(const f32x4v*)&in[(size_t)i * 4];
  short4v o = { f2bf(v.x), f2bf(v.y), f2bf(v.z), f2bf(v.w) };
  *(short4v*)&out[(size_t)i * 4] = o;
}

// ---------------- pipelined 256x128 bf16 GEMM, B^T input ----------------
// R9 schedule with BK 64->32: slot = A 256x32 (8192 shorts) + B 128x32
// (4096 shorts) = 24 KB; 3-slot ring = 72 KB -> 2 blocks/CU (16 waves/CU,
// cross-block TLP covers barrier/drain stalls). Ledger: 3 gloads/slot;
// stage slot t+2 at iter t; vmcnt(3) = slot t+1 landed; tail vmcnt(0).
// Write-after-read proof as R3/R9: slot t+2 region (held t-1) was fully
// read before iter t-1's trailing barrier. Swizzle: phys 16B-slot =
// logical ^ (row&3) on both stage-source and read (uniform 8-way b128 =
// minimum aliasing).
template <int EPI>
__global__ __launch_bounds__(512, 4) void gemm_p(
    const short* __restrict__ A, const short* __restrict__ Bt,
    int M, int N, int K, float* __restrict__ Cf,
    const float* __restrict__ cosb, const float* __restrict__ sinb,
    short* __restrict__ Qo, short* __restrict__ Ko, short* __restrict__ Vt) {
  __shared__ __align__(16) short lds[3][12288];
  const int t = threadIdx.x;
  const int wid = t >> 6, l = t & 63;
  const int lr = l & 15, lg = l >> 4;
  const int wm = wid >> 1, wn = wid & 1;

  int bid = blockIdx.x;
  const int nwg = gridDim.x;
  bid = (bid & 7) * (nwg >> 3) + (bid >> 3);   // bijective XCD remap (nwg%8==0)
  const int nbx = N >> 7;
  const int bx = bid % nbx, by = bid / nbx;
  const int brow = by * 256, bcol = bx * 128;

  // staging: thread t -> row (t>>2) (+128 for A's second issue), 16B slot
  // (t&3) linear dest; source logical slot = (t&3) ^ (row&3).
  const int scol = ((t & 3) ^ ((t >> 2) & 3)) * 8;
  const short* As = A  + (size_t)(brow + (t >> 2)) * K + scol;
  const short* Bs = Bt + (size_t)(bcol + (t >> 2)) * K + scol;

  f32x4 acc[4][4] = {};

  const int ns = K >> 5;   // BK=32 slots

#define STAGE(slot, kt) do {                                                \
    gload_lds16(As + (size_t)(kt),           &lds[slot][t * 8]);            \
    gload_lds16(As + (size_t)128 * K + (kt), &lds[slot][4096 + t * 8]);     \
    gload_lds16(Bs + (size_t)(kt),           &lds[slot][8192 + t * 8]);     \
  } while (0)

  // ---- prologue: stage slots 0,1 ----
  STAGE(0, 0);
  STAGE(1, 32);
  asm volatile("s_waitcnt vmcnt(3)" ::: "memory");   // slot 0 landed
  __builtin_amdgcn_s_barrier();

  const int xo = ((lg ^ (lr & 3)) << 3);             // read swizzle (shorts)
  const int arow = (wm * 64 + lr) * 32;
  const int brow_s = 8192 + (wn * 64 + lr) * 32;

  int slot = 0;
  for (int ss = 0; ss < ns; ++ss) {
    const int s2 = (slot + 2 >= 3) ? slot - 1 : slot + 2;
    bf16x8 af[4], bfr[4];

#pragma unroll
    for (int m = 0; m < 4; ++m)
      af[m] = *(const bf16x8*)&lds[slot][arow + m * 512 + xo];
#pragma unroll
    for (int n = 0; n < 4; ++n)
      bfr[n] = *(const bf16x8*)&lds[slot][brow_s + n * 512 + xo];
    if (ss + 2 < ns) STAGE(s2, (ss + 2) << 5);
    if (ss < ns - 2) asm volatile("s_waitcnt vmcnt(3)" ::: "memory");
    else             asm volatile("s_waitcnt vmcnt(0)" ::: "memory");
    __builtin_amdgcn_s_barrier();
    asm volatile("s_waitcnt lgkmcnt(0)" ::: "memory");
    __builtin_amdgcn_sched_barrier(0);
    __builtin_amdgcn_s_setprio(1);
#pragma unroll
    for (int m = 0; m < 4; ++m)
#pragma unroll
      for (int n = 0; n < 4; ++n)
        acc[m][n] = __builtin_amdgcn_mfma_f32_16x16x32_bf16(af[m], bfr[n], acc[m][n], 0, 0, 0);
    __builtin_amdgcn_s_setprio(0);
    __builtin_amdgcn_s_barrier();

    slot = (slot + 1 >= 3) ? 0 : slot + 1;
  }
#undef STAGE

  const int row0 = brow + wm * 64, col0 = bcol + wn * 64;
  if (EPI == 0) {
#pragma unroll
    for (int m = 0; m < 4; ++m)
#pragma unroll
      for (int n = 0; n < 4; ++n)
#pragma unroll
        for (int r = 0; r < 4; ++r)
          Cf[(size_t)(row0 + m * 16 + lg * 4 + r) * N + col0 + n * 16 + lr] = acc[m][n][r];
  } else {
    const int sec = col0 >> 11;
    const int headc = (col0 & 2047) >> 7;
    const bool rope = (sec < 2) && ((col0 & 127) == 0);
#pragma unroll
    for (int m = 0; m < 4; ++m) {
#pragma unroll
      for (int r = 0; r < 4; ++r) {
        const int s = row0 + m * 16 + lg * 4 + r;
        float v0 = acc[m][0][r], v1 = acc[m][1][r];
        float v2 = acc[m][2][r], v3 = acc[m][3][r];
        if (rope) {
          const int d0 = lr;
          float c0 = cosb[s * 32 + d0],      sn0 = sinb[s * 32 + d0];
          float c1 = cosb[s * 32 + d0 + 16], sn1 = sinb[s * 32 + d0 + 16];
          float t0 = v0 * c0 - v1 * sn0;
          float t1 = v1 * c1 + v0 * sn1;
          v0 = t0; v1 = t1;
        }
        float vv[4] = {v0, v1, v2, v3};
#pragma unroll
        for (int n = 0; n < 4; ++n) {
          const int col = col0 + n * 16 + lr;
          const int d = col & 127;
          if (sec == 0)
            Qo[((size_t)headc * S_LEN + s) * HD + d] = f2bf(vv[n] * 0.08838834764831845f);
          else if (sec == 1)
            Ko[((size_t)headc * S_LEN + s) * HD + d] = f2bf(vv[n]);
          else
            Vt[((size_t)headc * HD + d) * S_LEN + s] = f2bf(vv[n]);
        }
      }
    }
  }
}

// ---------------- sliding-window flash attention (R9 + T5 setprio) ------
__global__ __launch_bounds__(256) void attn_k(const short* __restrict__ Q,
                                              const short* __restrict__ Kk,
                                              const short* __restrict__ Vt,
                                              short* __restrict__ Ao) {
  __shared__ __align__(16) short Kl[2][64 * HD];
  __shared__ __align__(16) short Vl[2][HD * 64];
  __shared__ __align__(16) short Pl[4][16 * 72];
  const int head = blockIdx.y;
  int bxx = blockIdx.x;
  bxx = ((bxx & 7) << 3) | (bxx >> 3);           // XCD remap (bijective, 64=8x8)
  const int qb = bxx * 64;
  const int w = threadIdx.x >> 6, l = threadIdx.x & 63;
  const int lr = l & 15, lg = l >> 4;
  const int q0w = qb + w * 16;
  const short* Qh = Q  + (size_t)head * S_LEN * HD;
  const short* Kh = Kk + (size_t)head * S_LEN * HD;
  const short* Vh = Vt + (size_t)head * HD * S_LEN;

  bf16x8 qf[4];
#pragma unroll
  for (int kk = 0; kk < 4; ++kk)
    qf[kk] = *(const bf16x8*)&Qh[(size_t)(q0w + lr) * HD + kk * 32 + lg * 8];

  f32x4 oacc[8] = {};
  float mrow[4], lrow[4];
#pragma unroll
  for (int r = 0; r < 4; ++r) { mrow[r] = -1e30f; lrow[r] = 0.0f; }

  const int k_begin = (qb >= WIN) ? (qb - WIN) : 0;
  const int nt = (qb + 64 - k_begin) >> 6;
  const int swz = (lr & 7) << 4;

#define STAGE_KV(p, k0) do {                                                   \
    _Pragma("unroll")                                                          \
    for (int i = 0; i < 4; ++i) {                                              \
      const int row = i * 16 + w * 4 + (l >> 4);                               \
      gload_lds16(Kh + (size_t)((k0) + row) * HD + (((l & 15) ^ (row & 7)) * 8),\
                  &Kl[p][(i * 16 + w * 4) * HD]);                              \
    }                                                                          \
    _Pragma("unroll")                                                          \
    for (int i = 0; i < 4; ++i) {                                              \
      const int row = i * 32 + w * 8 + (l >> 3);                               \
      gload_lds16(Vh + (size_t)row * S_LEN + (k0) + (((l & 7) ^ (row & 7)) * 8),\
                  &Vl[p][(i * 32 + w * 8) * 64]);                              \
    }                                                                          \
  } while (0)

  STAGE_KV(0, k_begin);
  asm volatile("s_waitcnt vmcnt(0)" ::: "memory");
  __syncthreads();

  for (int tkv = 0; tkv < nt; ++tkv) {
    const int k0 = k_begin + tkv * 64;
    const int pl = tkv & 1;
    if (tkv + 1 < nt) STAGE_KV(pl ^ 1, k0 + 64);

    // ---- S = Q K^T (16 q x 64 keys) ----
    f32x4 sacc[4] = {};
#pragma unroll
    for (int nf = 0; nf < 4; ++nf) {
      const char* kb = (const char*)&Kl[pl][0] + (nf * 16 + lr) * 256;
      bf16x8 kf[4];
#pragma unroll
      for (int kk = 0; kk < 4; ++kk)
        kf[kk] = *(const bf16x8*)(kb + ((kk * 64 + lg * 16) ^ swz));
      __builtin_amdgcn_s_setprio(1);
#pragma unroll
      for (int kk = 0; kk < 4; ++kk)
        sacc[nf] = __builtin_amdgcn_mfma_f32_16x16x32_bf16(qf[kk], kf[kk], sacc[nf], 0, 0, 0);
      __builtin_amdgcn_s_setprio(0);
    }

    const bool full = (k0 + 63 <= q0w) && (k0 >= q0w + 15 - WIN);
    float scl[4];
#pragma unroll
    for (int r = 0; r < 4; ++r) {
      const int i = q0w + lg * 4 + r;
      float sv[4];
#pragma unroll
      for (int nf = 0; nf < 4; ++nf) sv[nf] = sacc[nf][r];
      if (!full) {
#pragma unroll
        for (int nf = 0; nf < 4; ++nf) {
          const int j = k0 + nf * 16 + lr;
          if (!((j <= i) && (j + WIN >= i))) sv[nf] = -1e30f;
        }
      }
      float mx = fmaxf(fmaxf(sv[0], sv[1]), fmaxf(sv[2], sv[3]));
#pragma unroll
      for (int d = 1; d < 16; d <<= 1) mx = fmaxf(mx, __shfl_xor(mx, d, 64));
      const float mn = fmaxf(mrow[r], mx);
      const float sc = __expf(mrow[r] - mn);
      mrow[r] = mn;
      float p[4], rs = 0.0f;
#pragma unroll
      for (int nf = 0; nf < 4; ++nf) { p[nf] = __expf(sv[nf] - mn); rs += p[nf]; }
#pragma unroll
      for (int d = 1; d < 16; d <<= 1) rs += __shfl_xor(rs, d, 64);
      lrow[r] = lrow[r] * sc + rs;
      scl[r] = sc;
#pragma unroll
      for (int nf = 0; nf < 4; ++nf)
        Pl[w][(lg * 4 + r) * 72 + nf * 16 + lr] = f2bf(p[nf]);
    }
#pragma unroll
    for (int df = 0; df < 8; ++df)
#pragma unroll
      for (int r = 0; r < 4; ++r) oacc[df][r] *= scl[r];

    bf16x8 pa[2];
#pragma unroll
    for (int kk2 = 0; kk2 < 2; ++kk2)
      pa[kk2] = *(const bf16x8*)&Pl[w][lr * 72 + kk2 * 32 + lg * 8];

    // ---- O += P V ----
#pragma unroll
    for (int df = 0; df < 8; ++df) {
      const char* vb = (const char*)&Vl[pl][0] + (df * 16 + lr) * 128;
      bf16x8 vfrag0 = *(const bf16x8*)(vb + ((0 * 64 + lg * 16) ^ swz));
      bf16x8 vfrag1 = *(const bf16x8*)(vb + ((1 * 64 + lg * 16) ^ swz));
      __builtin_amdgcn_s_setprio(1);
      oacc[df] = __builtin_amdgcn_mfma_f32_16x16x32_bf16(pa[0], vfrag0, oacc[df], 0, 0, 0);
      oacc[df] = __builtin_amdgcn_mfma_f32_16x16x32_bf16(pa[1], vfrag1, oacc[df], 0, 0, 0);
      __builtin_amdgcn_s_setprio(0);
    }

    if (tkv + 1 < nt) asm volatile("s_waitcnt vmcnt(0)" ::: "memory");
    __syncthreads();
  }
#undef STAGE_KV

  float inv[4];
#pragma unroll
  for (int r = 0; r < 4; ++r) inv[r] = 1.0f / lrow[r];
#pragma unroll
  for (int df = 0; df < 8; ++df)
#pragma unroll
    for (int r = 0; r < 4; ++r) {
      const int s = q0w + lg * 4 + r;
      Ao[(size_t)s * HDIM + head * HD + df * 16 + lr] = f2bf(oacc[df][r] * inv[r]);
    }
}

extern "C" void kernel_launch(void* const* d_in, const int* in_sizes, int n_in,
                              void* d_out, int out_size, void* d_ws, size_t ws_size,
                              hipStream_t stream) {
  const float* x    = (const float*)d_in[0];
  const float* cosb = (const float*)d_in[1];
  const float* sinb = (const float*)d_in[2];
  const float* nw   = (const float*)d_in[3];
  const float* qkvw = (const float*)d_in[4];
  const float* ow   = (const float*)d_in[5];
  float* out = (float*)d_out;

  short* ws = (short*)d_ws;
  short* xn = ws;
  short* wb = xn + (size_t)S_LEN * HDIM;
  short* Qb = wb + (size_t)3 * HDIM * HDIM;
  short* Kb = Qb + (size_t)NHEAD * S_LEN * HD;
  short* Vb = Kb + (size_t)NHEAD * S_LEN * HD;
  short* Ao = xn;

  rmsnorm_k<<<S_LEN, 256, 0, stream>>>(x, nw, xn);
  cvt_k<<<(3 * HDIM * HDIM / 4 + 255) / 256, 256, 0, stream>>>(qkvw, wb, 3 * HDIM * HDIM / 4);
  gemm_p<1><<<(3 * HDIM / 128) * (S_LEN / 256), 512, 0, stream>>>(
      xn, wb, S_LEN, 3 * HDIM, HDIM, nullptr, cosb, sinb, Qb, Kb, Vb);
  cvt_k<<<(HDIM * HDIM / 4 + 255) / 256, 256, 0, stream>>>(ow, wb, HDIM * HDIM / 4);
  attn_k<<<dim3(S_LEN / 64, NHEAD), 256, 0, stream>>>(Qb, Kb, Vb, Ao);
  gemm_p<0><<<(HDIM / 128) * (S_LEN / 256), 512, 0, stream>>>(
      Ao, wb, S_LEN, HDIM, HDIM, out, nullptr, nullptr, nullptr, nullptr, nullptr);
}

// Round 11
// 320.746 us; speedup vs baseline: 1.0085x; 1.0085x over previous
//
#include <hip/hip_runtime.h>
#include <stdint.h>

#define S_LEN 4096
#define HDIM  2048
#define NHEAD 16
#define HD    128
#define WIN   1024

typedef float  f32x4  __attribute__((ext_vector_type(4)));
typedef float  f32x4v __attribute__((ext_vector_type(4)));
typedef __bf16 bf16x8 __attribute__((ext_vector_type(8)));
typedef short  short8 __attribute__((ext_vector_type(8)));
typedef short  short4v __attribute__((ext_vector_type(4)));

static __device__ __forceinline__ short f2bf(float f) {
  union { float f; uint32_t u; } v; v.f = f;
  uint32_t r = (v.u + 0x7FFFu + ((v.u >> 16) & 1u)) >> 16;
  return (short)(uint16_t)r;
}

static __device__ __forceinline__ void gload_lds16(const void* g, void* l) {
  __builtin_amdgcn_global_load_lds((__attribute__((address_space(1))) void*)g,
                                   (__attribute__((address_space(3))) void*)l,
                                   16, 0, 0);
}

// ------- fused prep: rmsnorm (blocks 0..4095) + qkv_w f32->bf16 cvt -------
__global__ __launch_bounds__(256) void prep_k(const float* __restrict__ x,
                                              const float* __restrict__ w,
                                              short* __restrict__ xn,
                                              const float* __restrict__ qkvw,
                                              short* __restrict__ wbq) {
  const int b = blockIdx.x;
  const int t = threadIdx.x;
  if (b < S_LEN) {
    const float* xr = x + (size_t)b * HDIM;
    f32x4v a = *(const f32x4v*)&xr[t * 8];
    f32x4v bb = *(const f32x4v*)&xr[t * 8 + 4];
    float ss = a.x*a.x + a.y*a.y + a.z*a.z + a.w*a.w
             + bb.x*bb.x + bb.y*bb.y + bb.z*bb.z + bb.w*bb.w;
#pragma unroll
    for (int d = 1; d < 64; d <<= 1) ss += __shfl_xor(ss, d, 64);
    __shared__ float sred[4];
    if ((t & 63) == 0) sred[t >> 6] = ss;
    __syncthreads();
    float tot = sred[0] + sred[1] + sred[2] + sred[3];
    float rs = rsqrtf(tot * (1.0f / HDIM) + 1e-5f);
    float vv[8] = {a.x, a.y, a.z, a.w, bb.x, bb.y, bb.z, bb.w};
    const float* wp = w + t * 8;
    short8 o;
#pragma unroll
    for (int j = 0; j < 8; ++j) o[j] = f2bf(vv[j] * rs * wp[j]);
    *(short8*)&xn[(size_t)b * HDIM + t * 8] = o;
  } else {
    const size_t i = (size_t)(b - S_LEN) * 256 + t;   // < 3*H*H/4
    f32x4v v = *(const f32x4v*)&qkvw[i * 4];
    short4v o = { f2bf(v.x), f2bf(v.y), f2bf(v.z), f2bf(v.w) };
    *(short4v*)&wbq[i * 4] = o;
  }
}

// ---------------- f32 -> bf16 weight convert ----------------
__global__ __launch_bounds__(256) void cvt_k(const float* __restrict__ in,
                                             short* __restrict__ out, int n4) {
  int i = blockIdx.x * 256 + threadIdx.x;
  if (i >= n4) return;
  f32x4v v = *(const f32x4v*)&in[(size_t)i * 4];
  short4v o = { f2bf(v.x), f2bf(v.y), f2bf(v.z), f2bf(v.w) };
  *(short4v*)&out[(size_t)i * 4] = o;
}

// ---------------- pipelined 256x128 bf16 GEMM, B^T input ----------------
// LOCKED (R10-measured best: QKV 146.6us, 2 blocks/CU, MfmaUtil 30%).
// BK=32: slot = A 256x32 + B 128x32 = 24 KB; 3-slot ring = 72 KB.
// Ledger: 3 gloads/slot; stage slot t+2 at iter t; vmcnt(3); tail vmcnt(0).
template <int EPI>
__global__ __launch_bounds__(512, 4) void gemm_p(
    const short* __restrict__ A, const short* __restrict__ Bt,
    int M, int N, int K, float* __restrict__ Cf,
    const float* __restrict__ cosb, const float* __restrict__ sinb,
    short* __restrict__ Qo, short* __restrict__ Ko, short* __restrict__ Vt) {
  __shared__ __align__(16) short lds[3][12288];
  const int t = threadIdx.x;
  const int wid = t >> 6, l = t & 63;
  const int lr = l & 15, lg = l >> 4;
  const int wm = wid >> 1, wn = wid & 1;

  int bid = blockIdx.x;
  const int nwg = gridDim.x;
  bid = (bid & 7) * (nwg >> 3) + (bid >> 3);   // bijective XCD remap (nwg%8==0)
  const int nbx = N >> 7;
  const int bx = bid % nbx, by = bid / nbx;
  const int brow = by * 256, bcol = bx * 128;

  const int scol = ((t & 3) ^ ((t >> 2) & 3)) * 8;
  const short* As = A  + (size_t)(brow + (t >> 2)) * K + scol;
  const short* Bs = Bt + (size_t)(bcol + (t >> 2)) * K + scol;

  f32x4 acc[4][4] = {};

  const int ns = K >> 5;   // BK=32 slots

#define STAGE(slot, kt) do {                                                \
    gload_lds16(As + (size_t)(kt),           &lds[slot][t * 8]);            \
    gload_lds16(As + (size_t)128 * K + (kt), &lds[slot][4096 + t * 8]);     \
    gload_lds16(Bs + (size_t)(kt),           &lds[slot][8192 + t * 8]);     \
  } while (0)

  // ---- prologue: stage slots 0,1 ----
  STAGE(0, 0);
  STAGE(1, 32);
  asm volatile("s_waitcnt vmcnt(3)" ::: "memory");   // slot 0 landed
  __builtin_amdgcn_s_barrier();

  const int xo = ((lg ^ (lr & 3)) << 3);             // read swizzle (shorts)
  const int arow = (wm * 64 + lr) * 32;
  const int brow_s = 8192 + (wn * 64 + lr) * 32;

  int slot = 0;
  for (int ss = 0; ss < ns; ++ss) {
    const int s2 = (slot + 2 >= 3) ? slot - 1 : slot + 2;
    bf16x8 af[4], bfr[4];

#pragma unroll
    for (int m = 0; m < 4; ++m)
      af[m] = *(const bf16x8*)&lds[slot][arow + m * 512 + xo];
#pragma unroll
    for (int n = 0; n < 4; ++n)
      bfr[n] = *(const bf16x8*)&lds[slot][brow_s + n * 512 + xo];
    if (ss + 2 < ns) STAGE(s2, (ss + 2) << 5);
    if (ss < ns - 2) asm volatile("s_waitcnt vmcnt(3)" ::: "memory");
    else             asm volatile("s_waitcnt vmcnt(0)" ::: "memory");
    __builtin_amdgcn_s_barrier();
    asm volatile("s_waitcnt lgkmcnt(0)" ::: "memory");
    __builtin_amdgcn_sched_barrier(0);
    __builtin_amdgcn_s_setprio(1);
#pragma unroll
    for (int m = 0; m < 4; ++m)
#pragma unroll
      for (int n = 0; n < 4; ++n)
        acc[m][n] = __builtin_amdgcn_mfma_f32_16x16x32_bf16(af[m], bfr[n], acc[m][n], 0, 0, 0);
    __builtin_amdgcn_s_setprio(0);
    __builtin_amdgcn_s_barrier();

    slot = (slot + 1 >= 3) ? 0 : slot + 1;
  }
#undef STAGE

  const int row0 = brow + wm * 64, col0 = bcol + wn * 64;
  if (EPI == 0) {
#pragma unroll
    for (int m = 0; m < 4; ++m)
#pragma unroll
      for (int n = 0; n < 4; ++n)
#pragma unroll
        for (int r = 0; r < 4; ++r)
          Cf[(size_t)(row0 + m * 16 + lg * 4 + r) * N + col0 + n * 16 + lr] = acc[m][n][r];
  } else {
    const int sec = col0 >> 11;
    const int headc = (col0 & 2047) >> 7;
    const bool rope = (sec < 2) && ((col0 & 127) == 0);
#pragma unroll
    for (int m = 0; m < 4; ++m) {
#pragma unroll
      for (int r = 0; r < 4; ++r) {
        const int s = row0 + m * 16 + lg * 4 + r;
        float v0 = acc[m][0][r], v1 = acc[m][1][r];
        float v2 = acc[m][2][r], v3 = acc[m][3][r];
        if (rope) {
          const int d0 = lr;
          float c0 = cosb[s * 32 + d0],      sn0 = sinb[s * 32 + d0];
          float c1 = cosb[s * 32 + d0 + 16], sn1 = sinb[s * 32 + d0 + 16];
          float t0 = v0 * c0 - v1 * sn0;
          float t1 = v1 * c1 + v0 * sn1;
          v0 = t0; v1 = t1;
        }
        float vv[4] = {v0, v1, v2, v3};
#pragma unroll
        for (int n = 0; n < 4; ++n) {
          const int col = col0 + n * 16 + lr;
          const int d = col & 127;
          if (sec == 0)
            Qo[((size_t)headc * S_LEN + s) * HD + d] = f2bf(vv[n] * 0.08838834764831845f);
          else if (sec == 1)
            Ko[((size_t)headc * S_LEN + s) * HD + d] = f2bf(vv[n]);
          else
            Vt[((size_t)headc * HD + d) * S_LEN + s] = f2bf(vv[n]);
        }
      }
    }
  }
}

// ---------------- sliding-window flash attention (R9 verbatim) ----------
// grid (S/64, NHEAD), 4 waves/block, wave w owns 16 q-rows. K/V tiles
// double-buffered: STAGE(t+1) issued BEFORE computing tile t; single
// vmcnt(0)+barrier per iteration. No setprio (R10 measured it -15%).
__global__ __launch_bounds__(256) void attn_k(const short* __restrict__ Q,
                                              const short* __restrict__ Kk,
                                              const short* __restrict__ Vt,
                                              short* __restrict__ Ao) {
  __shared__ __align__(16) short Kl[2][64 * HD];
  __shared__ __align__(16) short Vl[2][HD * 64];
  __shared__ __align__(16) short Pl[4][16 * 72];
  const int head = blockIdx.y;
  int bxx = blockIdx.x;
  bxx = ((bxx & 7) << 3) | (bxx >> 3);           // XCD remap (bijective, 64=8x8)
  const int qb = bxx * 64;
  const int w = threadIdx.x >> 6, l = threadIdx.x & 63;
  const int lr = l & 15, lg = l >> 4;
  const int q0w = qb + w * 16;
  const short* Qh = Q  + (size_t)head * S_LEN * HD;
  const short* Kh = Kk + (size_t)head * S_LEN * HD;
  const short* Vh = Vt + (size_t)head * HD * S_LEN;

  bf16x8 qf[4];
#pragma unroll
  for (int kk = 0; kk < 4; ++kk)
    qf[kk] = *(const bf16x8*)&Qh[(size_t)(q0w + lr) * HD + kk * 32 + lg * 8];

  f32x4 oacc[8] = {};
  float mrow[4], lrow[4];
#pragma unroll
  for (int r = 0; r < 4; ++r) { mrow[r] = -1e30f; lrow[r] = 0.0f; }

  const int k_begin = (qb >= WIN) ? (qb - WIN) : 0;
  const int nt = (qb + 64 - k_begin) >> 6;
  const int swz = (lr & 7) << 4;

#define STAGE_KV(p, k0) do {                                                   \
    _Pragma("unroll")                                                          \
    for (int i = 0; i < 4; ++i) {                                              \
      const int row = i * 16 + w * 4 + (l >> 4);                               \
      gload_lds16(Kh + (size_t)((k0) + row) * HD + (((l & 15) ^ (row & 7)) * 8),\
                  &Kl[p][(i * 16 + w * 4) * HD]);                              \
    }                                                                          \
    _Pragma("unroll")                                                          \
    for (int i = 0; i < 4; ++i) {                                              \
      const int row = i * 32 + w * 8 + (l >> 3);                               \
      gload_lds16(Vh + (size_t)row * S_LEN + (k0) + (((l & 7) ^ (row & 7)) * 8),\
                  &Vl[p][(i * 32 + w * 8) * 64]);                              \
    }                                                                          \
  } while (0)

  STAGE_KV(0, k_begin);
  asm volatile("s_waitcnt vmcnt(0)" ::: "memory");
  __syncthreads();

  for (int tkv = 0; tkv < nt; ++tkv) {
    const int k0 = k_begin + tkv * 64;
    const int pl = tkv & 1;
    if (tkv + 1 < nt) STAGE_KV(pl ^ 1, k0 + 64);

    // ---- S = Q K^T (16 q x 64 keys) ----
    f32x4 sacc[4] = {};
#pragma unroll
    for (int nf = 0; nf < 4; ++nf) {
      const char* kb = (const char*)&Kl[pl][0] + (nf * 16 + lr) * 256;
      bf16x8 kf[4];
#pragma unroll
      for (int kk = 0; kk < 4; ++kk)
        kf[kk] = *(const bf16x8*)(kb + ((kk * 64 + lg * 16) ^ swz));
#pragma unroll
      for (int kk = 0; kk < 4; ++kk)
        sacc[nf] = __builtin_amdgcn_mfma_f32_16x16x32_bf16(qf[kk], kf[kk], sacc[nf], 0, 0, 0);
    }

    const bool full = (k0 + 63 <= q0w) && (k0 >= q0w + 15 - WIN);
    float scl[4];
#pragma unroll
    for (int r = 0; r < 4; ++r) {
      const int i = q0w + lg * 4 + r;
      float sv[4];
#pragma unroll
      for (int nf = 0; nf < 4; ++nf) sv[nf] = sacc[nf][r];
      if (!full) {
#pragma unroll
        for (int nf = 0; nf < 4; ++nf) {
          const int j = k0 + nf * 16 + lr;
          if (!((j <= i) && (j + WIN >= i))) sv[nf] = -1e30f;
        }
      }
      float mx = fmaxf(fmaxf(sv[0], sv[1]), fmaxf(sv[2], sv[3]));
#pragma unroll
      for (int d = 1; d < 16; d <<= 1) mx = fmaxf(mx, __shfl_xor(mx, d, 64));
      const float mn = fmaxf(mrow[r], mx);
      const float sc = __expf(mrow[r] - mn);
      mrow[r] = mn;
      float p[4], rs = 0.0f;
#pragma unroll
      for (int nf = 0; nf < 4; ++nf) { p[nf] = __expf(sv[nf] - mn); rs += p[nf]; }
#pragma unroll
      for (int d = 1; d < 16; d <<= 1) rs += __shfl_xor(rs, d, 64);
      lrow[r] = lrow[r] * sc + rs;
      scl[r] = sc;
#pragma unroll
      for (int nf = 0; nf < 4; ++nf)
        Pl[w][(lg * 4 + r) * 72 + nf * 16 + lr] = f2bf(p[nf]);
    }
#pragma unroll
    for (int df = 0; df < 8; ++df)
#pragma unroll
      for (int r = 0; r < 4; ++r) oacc[df][r] *= scl[r];

    bf16x8 pa[2];
#pragma unroll
    for (int kk2 = 0; kk2 < 2; ++kk2)
      pa[kk2] = *(const bf16x8*)&Pl[w][lr * 72 + kk2 * 32 + lg * 8];

    // ---- O += P V ----
#pragma unroll
    for (int df = 0; df < 8; ++df) {
      const char* vb = (const char*)&Vl[pl][0] + (df * 16 + lr) * 128;
#pragma unroll
      for (int kk2 = 0; kk2 < 2; ++kk2) {
        bf16x8 vfrag = *(const bf16x8*)(vb + ((kk2 * 64 + lg * 16) ^ swz));
        oacc[df] = __builtin_amdgcn_mfma_f32_16x16x32_bf16(pa[kk2], vfrag, oacc[df], 0, 0, 0);
      }
    }

    if (tkv + 1 < nt) asm volatile("s_waitcnt vmcnt(0)" ::: "memory");
    __syncthreads();
  }
#undef STAGE_KV

  float inv[4];
#pragma unroll
  for (int r = 0; r < 4; ++r) inv[r] = 1.0f / lrow[r];
#pragma unroll
  for (int df = 0; df < 8; ++df)
#pragma unroll
    for (int r = 0; r < 4; ++r) {
      const int s = q0w + lg * 4 + r;
      Ao[(size_t)s * HDIM + head * HD + df * 16 + lr] = f2bf(oacc[df][r] * inv[r]);
    }
}

extern "C" void kernel_launch(void* const* d_in, const int* in_sizes, int n_in,
                              void* d_out, int out_size, void* d_ws, size_t ws_size,
                              hipStream_t stream) {
  const float* x    = (const float*)d_in[0];
  const float* cosb = (const float*)d_in[1];
  const float* sinb = (const float*)d_in[2];
  const float* nw   = (const float*)d_in[3];
  const float* qkvw = (const float*)d_in[4];
  const float* ow   = (const float*)d_in[5];
  float* out = (float*)d_out;

  short* ws = (short*)d_ws;
  short* xn = ws;
  short* wb = xn + (size_t)S_LEN * HDIM;
  short* Qb = wb + (size_t)3 * HDIM * HDIM;
  short* Kb = Qb + (size_t)NHEAD * S_LEN * HD;
  short* Vb = Kb + (size_t)NHEAD * S_LEN * HD;
  short* Ao = xn;

  prep_k<<<S_LEN + 3 * HDIM * HDIM / 1024, 256, 0, stream>>>(x, nw, xn, qkvw, wb);
  gemm_p<1><<<(3 * HDIM / 128) * (S_LEN / 256), 512, 0, stream>>>(
      xn, wb, S_LEN, 3 * HDIM, HDIM, nullptr, cosb, sinb, Qb, Kb, Vb);
  cvt_k<<<(HDIM * HDIM / 4 + 255) / 256, 256, 0, stream>>>(ow, wb, HDIM * HDIM / 4);
  attn_k<<<dim3(S_LEN / 64, NHEAD), 256, 0, stream>>>(Qb, Kb, Vb, Ao);
  gemm_p<0><<<(HDIM / 128) * (S_LEN / 256), 512, 0, stream>>>(
      Ao, wb, S_LEN, HDIM, HDIM, out, nullptr, nullptr, nullptr, nullptr, nullptr);
}